// Round 2
// baseline (227.750 us; speedup 1.0000x reference)
//
#include <hip/hip_runtime.h>
#include <hip/hip_bf16.h>

#define NUM_CLASSES 80
#define BATCH 8
#define N20 1200
#define N40 4800
#define N80 19200
#define NANCH 25200
#define NEGV  -1000000000.0f
#define SCORE_THR 0.25f
#define NBINS 4096
#define CAP 2048            // per-batch candidate-list capacity (expected ~510)
#define THR_LIST 64.0f      // list threshold; bin(64.0f) = 0x428 = 1064 exactly
#define THR_BIN 1064
#define REGC 512            // candidates held in wave-0 registers (8/lane)

// ---------------------------------------------------------------------------
// Kernel 1: class argmax + score; coalesced via LDS stage; appends candidates
// with score >= 64.0 to per-batch global lists.
// Block = 320 threads = 80 anchors of one (batch, head) segment.
// ---------------------------------------------------------------------------
__global__ __launch_bounds__(320) void score_kernel(
        const float* __restrict__ p20, const float* __restrict__ c20,
        const float* __restrict__ p40, const float* __restrict__ c40,
        const float* __restrict__ p80, const float* __restrict__ c80,
        float* __restrict__ scores, unsigned* __restrict__ cand_cnt,
        unsigned long long* __restrict__ cand_keys) {
    __shared__ float4 cls_lds[80 * 21];    // 80 anchors x 20 float4, pad +1 f4/row
    __shared__ float p_lds[80];
    __shared__ float s_lds[80];

    const int t = threadIdx.x;
    const int blk = blockIdx.x;
    const int b = blk / 315;
    const int r = blk - b * 315;

    const float *cbase, *pbase;
    int nbase;
    if (r < 15) {
        int a0 = r * 80;
        cbase = c20 + ((size_t)b * N20 + a0) * NUM_CLASSES;
        pbase = p20 + (size_t)b * N20 + a0;
        nbase = a0;
    } else if (r < 75) {
        int a0 = (r - 15) * 80;
        cbase = c40 + ((size_t)b * N40 + a0) * NUM_CLASSES;
        pbase = p40 + (size_t)b * N40 + a0;
        nbase = N20 + a0;
    } else {
        int a0 = (r - 75) * 80;
        cbase = c80 + ((size_t)b * N80 + a0) * NUM_CLASSES;
        pbase = p80 + (size_t)b * N80 + a0;
        nbase = N20 + N40 + a0;
    }

    // stage 80 anchors x 80 classes = 1600 float4, fully coalesced
    const float4* c4 = (const float4*)cbase;
#pragma unroll
    for (int k = 0; k < 5; k++) {
        int u = t + k * 320;              // 0..1599
        float4 v = c4[u];
        int a = u / 20, w = u - a * 20;
        cls_lds[a * 21 + w] = v;
    }
    if (t < 80) p_lds[t] = pbase[t];
    __syncthreads();

    const int a = t >> 2, q = t & 3;      // 4 lanes per anchor, within-wave groups
    const float4* row = cls_lds + a * 21 + q * 5;
    float best = -INFINITY;
    int bi = 0;
#pragma unroll
    for (int j = 0; j < 5; j++) {
        float4 v = row[j];
        int base = q * 20 + j * 4;
        if (v.x > best) { best = v.x; bi = base; }
        if (v.y > best) { best = v.y; bi = base + 1; }
        if (v.z > best) { best = v.z; bi = base + 2; }
        if (v.w > best) { best = v.w; bi = base + 3; }
    }
#pragma unroll
    for (int d = 1; d <= 2; d <<= 1) {
        float ov = __shfl_xor(best, d);
        int   oi = __shfl_xor(bi, d);
        if (ov > best || (ov == best && oi < bi)) { best = ov; bi = oi; }
    }
    if (q == 0) {
        float p = p_lds[a];
        float s = __fmul_rn(p, (float)bi);          // exact fp32, matches np
        s_lds[a] = (s > SCORE_THR) ? s : NEGV;
        if (s >= THR_LIST) {
            int n = nbase + a;
            unsigned pos = atomicAdd(&cand_cnt[b], 1u);
            if (pos < (unsigned)CAP)
                cand_keys[(size_t)b * CAP + pos] =
                    ((unsigned long long)__float_as_uint(s) << 32)
                  | (unsigned long long)(0xFFFFFFFFu - (unsigned)n);
        }
    }
    __syncthreads();
    if (t < 80) scores[(size_t)b * NANCH + nbase + t] = s_lds[t];
}

// exact IEEE fp32 (no FMA contraction) "IoU > 0.5" — matches numpy ref
__device__ __forceinline__ bool iou_gt(const float4 A, float areaA, const float4 Bx, float areaB) {
    float ih = fmaxf(__fsub_rn(fminf(A.z, Bx.z), fmaxf(A.x, Bx.x)), 0.0f);
    float iw = fmaxf(__fsub_rn(fminf(A.w, Bx.w), fmaxf(A.y, Bx.y)), 0.0f);
    float inter = __fmul_rn(ih, iw);
    float uni = __fsub_rn(__fadd_rn(areaA, areaB), inter);
    if (!(uni > 0.0f)) return false;
    return __fdiv_rn(inter, uni) > 0.5f;
}

__device__ __forceinline__ float4 load_box(int b, int n,
        const float* b20, const float* b40, const float* b80) {
    if (n < N20)       return ((const float4*)b20)[(size_t)b * N20 + n];
    if (n < N20 + N40) return ((const float4*)b40)[(size_t)b * N40 + (n - N20)];
    return ((const float4*)b80)[(size_t)b * N80 + (n - N20 - N40)];
}

// one greedy step: lanes 0..63 test candidate against their held survivors
__device__ __forceinline__ void try_accept(float4 cb, float aB, float s,
        int t, int& v, float4& sb0, float& sa0, float4& sb1, float& sa1,
        int b, float* __restrict__ out) {
    bool sup = false;
    if (t < v)      sup = iou_gt(sb0, sa0, cb, aB);
    if (t + 64 < v) sup = sup || iou_gt(sb1, sa1, cb, aB);
    if (!__any(sup)) {
        if (v < 64) { if (t == v)      { sb0 = cb; sa0 = aB; } }
        else        { if (t == v - 64) { sb1 = cb; sa1 = aB; } }
        if (t == 0) {
            float* row = out + ((size_t)b * 100 + v) * 6;
            row[0] = fminf(fmaxf(cb.x, 0.f), 1.f);
            row[1] = fminf(fmaxf(cb.y, 0.f), 1.f);
            row[2] = fminf(fmaxf(cb.z, 0.f), 1.f);
            row[3] = fminf(fmaxf(cb.w, 0.f), 1.f);
            row[4] = s;
            row[5] = 0.f;
        }
        v++;
    }
}

// ---------------------------------------------------------------------------
// Kernel 2: per-batch exact greedy NMS. Hot path: rank-sort the prebuilt
// >=64.0 candidate list, walk from registers. Cold path (v<100): exact
// histogram chunk loop over remaining score range.
// ---------------------------------------------------------------------------
__global__ __launch_bounds__(256) void nms_kernel(
        const float* __restrict__ scores_g,
        const unsigned* __restrict__ cand_cnt,
        const unsigned long long* __restrict__ cand_keys,
        const float* __restrict__ b20, const float* __restrict__ b40, const float* __restrict__ b80,
        float* __restrict__ out) {
    __shared__ unsigned long long skraw[CAP];   // 16 KB
    __shared__ unsigned long long ssort[CAP];   // 16 KB
    __shared__ unsigned hist[NBINS];            // 16 KB (fallback only)
    __shared__ float4 candbox[256];             // 4 KB  (fallback only)
    __shared__ unsigned segT[256];
    __shared__ int sh_V, sh_lo, sh_hi;
    __shared__ unsigned sh_counter, sh_done, sh_total;

    const int t = threadIdx.x;
    const int b = blockIdx.x;
    const float* sc = scores_g + (size_t)b * NANCH;

    const unsigned cnt_raw = cand_cnt[b];
    const bool use_list = (cnt_raw <= (unsigned)CAP);
    const int cnt = use_list ? (int)cnt_raw : 0;

    for (int i = t; i < cnt; i += 256) skraw[i] = cand_keys[(size_t)b * CAP + i];
    if (t == 0) sh_V = 0;
    __syncthreads();

    // rank sort, descending (keys unique: idx in low word)
    for (int c = t; c < cnt; c += 256) {
        unsigned long long mykey = skraw[c];
        int rank = 0;
#pragma unroll 4
        for (int j = 0; j < cnt; j++) rank += (skraw[j] > mykey) ? 1 : 0;
        ssort[rank] = mykey;
    }
    __syncthreads();

    // survivor state: lane l holds survivors l and l+64
    float4 sb0 = make_float4(0.f, 0.f, 0.f, 0.f), sb1 = sb0;
    float sa0 = 0.f, sa1 = 0.f;
    int v = 0;

    const int lim = min(cnt, REGC);
    if (t < 64) {
        // gather top-512 candidates into registers (8 per lane)
        float4 cb_[8]; float ca_[8], cs_[8];
#pragma unroll
        for (int k = 0; k < 8; k++) {
            int p = k * 64 + t;
            if (p < lim) {
                unsigned long long key = ssort[p];
                int n = (int)(0xFFFFFFFFu - (unsigned)(key & 0xFFFFFFFFull));
                float4 bx = load_box(b, n, b20, b40, b80);
                cb_[k] = bx;
                ca_[k] = __fmul_rn(__fsub_rn(bx.z, bx.x), __fsub_rn(bx.w, bx.y));
                cs_[k] = __uint_as_float((unsigned)(key >> 32));
            }
        }
        // walk in sorted order, candidate broadcast via shfl
#pragma unroll
        for (int seg = 0; seg < 8; seg++) {
            const int base = seg * 64;
            if (base >= lim) break;
            const int end = min(lim, base + 64) - base;
            float4 C = cb_[seg]; float A = ca_[seg], S = cs_[seg];
            for (int l = 0; l < end && v < 100; l++) {
                float4 cb;
                cb.x = __shfl(C.x, l); cb.y = __shfl(C.y, l);
                cb.z = __shfl(C.z, l); cb.w = __shfl(C.w, l);
                float aB = __shfl(A, l);
                float s  = __shfl(S, l);
                try_accept(cb, aB, s, t, v, sb0, sa0, sb1, sa1, b, out);
            }
        }
        // rare: list longer than REGC and still short of 100 survivors
        for (int i = REGC; i < cnt && v < 100; i++) {
            unsigned long long key = ssort[i];
            int n = (int)(0xFFFFFFFFu - (unsigned)(key & 0xFFFFFFFFull));
            float4 cb = load_box(b, n, b20, b40, b80);
            float aB = __fmul_rn(__fsub_rn(cb.z, cb.x), __fsub_rn(cb.w, cb.y));
            float s = __uint_as_float((unsigned)(key >> 32));
            try_accept(cb, aB, s, t, v, sb0, sa0, sb1, sa1, b, out);
        }
        if (t == 0) sh_V = v;
    }
    __syncthreads();

    // ---------------- exact fallback (never taken with this data) ----------
    if (sh_V < 100) {
        const int hi_start = use_list ? THR_BIN : NBINS;
        for (int i = t; i < NBINS; i += 256) hist[i] = 0u;
        if (t == 0) { sh_done = 0u; sh_hi = hi_start; }
        __syncthreads();
        for (int i = t; i < NANCH; i += 256) {
            float s = sc[i];
            if (s > SCORE_THR) {
                int bin = (int)(__float_as_uint(s) >> 20);
                if (bin < hi_start) atomicAdd(&hist[bin], 1u);
            }
        }
        __syncthreads();
        // suffix sums: thread owns bins [16t, 16t+16)
        unsigned loc[16];
#pragma unroll
        for (int k = 0; k < 16; k++) loc[k] = hist[t * 16 + k];
#pragma unroll
        for (int k = 14; k >= 0; k--) loc[k] += loc[k + 1];
        segT[t] = loc[0];
        __syncthreads();
        for (int d = 1; d < 256; d <<= 1) {
            unsigned vv = (t + d < 256) ? segT[t + d] : 0u;
            __syncthreads();
            segT[t] += vv;
            __syncthreads();
        }
        {
            unsigned carry = (t < 255) ? segT[t + 1] : 0u;
#pragma unroll
            for (int k = 0; k < 16; k++) hist[t * 16 + k] = loc[k] + carry;
        }
        __syncthreads();
        if (t == 0) sh_total = hist[0];
        __syncthreads();

        for (int chunk = 0; chunk < 64; chunk++) {
            if (sh_V >= 100 || sh_done >= sh_total || sh_hi <= 0) break;
            const int hi = sh_hi;
            const unsigned Shi = (hi >= NBINS) ? 0u : hist[hi];
            if (t == 0) {
                int L = 0, R = hi;
                while (L < R) { int m = (L + R) >> 1; if (hist[m] - Shi <= (unsigned)CAP) R = m; else L = m + 1; }
                if (L >= hi) L = hi - 1;
                sh_lo = L;
                sh_counter = 0u;
            }
            __syncthreads();
            const int lo = sh_lo;
            for (int i = t; i < NANCH; i += 256) {
                float s = sc[i];
                if (s > SCORE_THR) {
                    int bin = (int)(__float_as_uint(s) >> 20);
                    if (bin >= lo && bin < hi) {
                        unsigned pos = atomicAdd(&sh_counter, 1u);
                        if (pos < (unsigned)CAP)
                            skraw[pos] = ((unsigned long long)__float_as_uint(s) << 32)
                                       | (unsigned long long)(0xFFFFFFFFu - (unsigned)i);
                    }
                }
            }
            __syncthreads();
            const int cc = min((int)sh_counter, CAP);
            for (int c = t; c < cc; c += 256) {
                unsigned long long mykey = skraw[c];
                int rank = 0;
                for (int j = 0; j < cc; j++) rank += (skraw[j] > mykey) ? 1 : 0;
                ssort[rank] = mykey;
            }
            __syncthreads();

            const int nwin = (cc + 255) / 256;
            for (int w = 0; w < nwin; w++) {
                if (sh_V >= 100) break;
                const int base = w * 256, lim2 = min(cc, base + 256);
                if (base + t < lim2) {
                    int n = (int)(0xFFFFFFFFu - (unsigned)(ssort[base + t] & 0xFFFFFFFFull));
                    candbox[t] = load_box(b, n, b20, b40, b80);
                }
                __syncthreads();
                if (t < 64) {
                    for (int i = base; i < lim2 && v < 100; i++) {
                        float4 cb = candbox[i - base];
                        float aB = __fmul_rn(__fsub_rn(cb.z, cb.x), __fsub_rn(cb.w, cb.y));
                        float s = __uint_as_float((unsigned)(ssort[i] >> 32));
                        try_accept(cb, aB, s, t, v, sb0, sa0, sb1, sa1, b, out);
                    }
                    if (t == 0) sh_V = v;
                }
                __syncthreads();
            }
            if (t == 0) { sh_done += (unsigned)cc; sh_hi = lo; }
            __syncthreads();
        }
    }
    __syncthreads();

    const int V = sh_V;
    for (int i = V * 6 + t; i < 600; i += 256) out[(size_t)b * 600 + i] = 0.f;
    if (t == 0) out[4800 + b] = (float)V;
}

extern "C" void kernel_launch(void* const* d_in, const int* in_sizes, int n_in,
                              void* d_out, int out_size, void* d_ws, size_t ws_size,
                              hipStream_t stream) {
    const float* b20 = (const float*)d_in[0];
    const float* p20 = (const float*)d_in[1];
    const float* c20 = (const float*)d_in[2];
    const float* b40 = (const float*)d_in[3];
    const float* p40 = (const float*)d_in[4];
    const float* c40 = (const float*)d_in[5];
    const float* b80 = (const float*)d_in[6];
    const float* p80 = (const float*)d_in[7];
    const float* c80 = (const float*)d_in[8];

    float*    scores   = (float*)d_ws;                                   // 806400 B
    unsigned* cand_cnt = (unsigned*)((char*)d_ws + 806400);              // 32 B
    unsigned long long* cand_keys =
        (unsigned long long*)((char*)d_ws + 806432);                     // 8*CAP*8 B

    hipMemsetAsync(cand_cnt, 0, 8 * sizeof(unsigned), stream);

    score_kernel<<<BATCH * 315, 320, 0, stream>>>(
        p20, c20, p40, c40, p80, c80, scores, cand_cnt, cand_keys);

    nms_kernel<<<BATCH, 256, 0, stream>>>(
        scores, cand_cnt, cand_keys, b20, b40, b80, (float*)d_out);
}

// Round 3
// 201.137 us; speedup vs baseline: 1.1323x; 1.1323x over previous
//
#include <hip/hip_runtime.h>
#include <hip/hip_bf16.h>

#define NUM_CLASSES 80
#define BATCH 8
#define N20 1200
#define N40 4800
#define N80 19200
#define NANCH 25200
#define NEGV  -1000000000.0f
#define SCORE_THR 0.25f
#define NBINS 4096
#define CAP 2048            // per-batch candidate capacity (expected ~510)
#define THR_LIST 64.0f      // list threshold; bin(64.0f) = 1064 exactly
#define THR_BIN 1064

typedef unsigned long long ull;

// ---------------------------------------------------------------------------
// Kernel 1: class argmax + score. 4 lanes/anchor, direct strided float4 loads
// (R1 pattern — measured faster than LDS staging). Wave-aggregated candidate
// append: one atomicAdd per wave via ballot + prefix-popcount.
// Grid: x = ceil(NANCH/64) anchor-blocks of 64 anchors, y = batch.
// ---------------------------------------------------------------------------
__global__ __launch_bounds__(256) void score_kernel(
        const float* __restrict__ p20, const float* __restrict__ c20,
        const float* __restrict__ p40, const float* __restrict__ c40,
        const float* __restrict__ p80, const float* __restrict__ c80,
        float* __restrict__ scores, unsigned* __restrict__ cand_cnt,
        ull* __restrict__ cand_keys) {
    const int t = threadIdx.x;
    const int lane = t & 63;
    const int b = blockIdx.y;
    const int q = t & 3;
    const int an = blockIdx.x * 64 + (t >> 2);
    const bool valid_an = (an < NANCH);
    const int n = valid_an ? an : (NANCH - 1);

    const float *cp, *pp;
    if (n < N20) {
        cp = c20 + ((size_t)b * N20 + n) * NUM_CLASSES;
        pp = p20 + (size_t)b * N20 + n;
    } else if (n < N20 + N40) {
        int a = n - N20;
        cp = c40 + ((size_t)b * N40 + a) * NUM_CLASSES;
        pp = p40 + (size_t)b * N40 + a;
    } else {
        int a = n - N20 - N40;
        cp = c80 + ((size_t)b * N80 + a) * NUM_CLASSES;
        pp = p80 + (size_t)b * N80 + a;
    }

    const float4* c4 = (const float4*)cp;
    float best = -INFINITY;
    int bi = 0;
#pragma unroll
    for (int j = 0; j < 5; j++) {
        float4 v = c4[q * 5 + j];
        int basei = q * 20 + j * 4;
        if (v.x > best) { best = v.x; bi = basei; }
        if (v.y > best) { best = v.y; bi = basei + 1; }
        if (v.z > best) { best = v.z; bi = basei + 2; }
        if (v.w > best) { best = v.w; bi = basei + 3; }
    }
    // merge across the 4 lanes of this anchor; first-max (lowest class) wins
#pragma unroll
    for (int d = 1; d <= 2; d <<= 1) {
        float ov = __shfl_xor(best, d);
        int   oi = __shfl_xor(bi, d);
        if (ov > best || (ov == best && oi < bi)) { best = ov; bi = oi; }
    }
    float p = *pp;
    float s = __fmul_rn(p, (float)bi);           // exact fp32, matches np
    float sval = (s > SCORE_THR) ? s : NEGV;

    // wave-aggregated candidate append (scores >= 64.0)
    bool pred = valid_an && (q == 0) && (s >= THR_LIST);
    ull mask = __ballot(pred);
    if (mask != 0ull) {
        int leader = (int)(__ffsll(mask) - 1);
        unsigned basep = 0;
        if (lane == leader) basep = atomicAdd(&cand_cnt[b], (unsigned)__popcll(mask));
        basep = __shfl(basep, leader);
        if (pred) {
            unsigned pos = basep + (unsigned)__popcll(mask & ((1ull << lane) - 1));
            if (pos < (unsigned)CAP)
                cand_keys[(size_t)b * CAP + pos] =
                    ((ull)__float_as_uint(s) << 32)
                  | (ull)(0xFFFFFFFFu - (unsigned)an);
        }
    }

    // coalesced score store: lanes 0..15 of each wave write 16 consecutive
    float svals = __shfl(sval, (lane & 15) * 4);
    int an0 = blockIdx.x * 64 + ((t >> 6) << 4);
    if (lane < 16 && an0 + lane < NANCH)
        scores[(size_t)b * NANCH + an0 + lane] = svals;
}

// exact IEEE fp32 (no FMA contraction) "IoU > 0.5" — matches numpy ref
__device__ __forceinline__ bool iou_gt(const float4 A, float areaA, const float4 Bx, float areaB) {
    float ih = fmaxf(__fsub_rn(fminf(A.z, Bx.z), fmaxf(A.x, Bx.x)), 0.0f);
    float iw = fmaxf(__fsub_rn(fminf(A.w, Bx.w), fmaxf(A.y, Bx.y)), 0.0f);
    float inter = __fmul_rn(ih, iw);
    float uni = __fsub_rn(__fadd_rn(areaA, areaB), inter);
    if (!(uni > 0.0f)) return false;
    return __fdiv_rn(inter, uni) > 0.5f;
}

__device__ __forceinline__ float4 load_box(int b, int n,
        const float* b20, const float* b40, const float* b80) {
    if (n < N20)       return ((const float4*)b20)[(size_t)b * N20 + n];
    if (n < N20 + N40) return ((const float4*)b40)[(size_t)b * N40 + (n - N20)];
    return ((const float4*)b80)[(size_t)b * N80 + (n - N20 - N40)];
}

// ---------------------------------------------------------------------------
// Group-of-64 greedy walk. Called by lanes t<64 of wave 0 only. Exact greedy
// NMS order: lane l owns candidate rank base+l; suppression-by-earlier
// resolved via per-lane 64-bit masks + wave-uniform ballot loop.
// ---------------------------------------------------------------------------
__device__ void walk_sorted(const ull* __restrict__ ssort, int cnt, int t, int b,
        int& v, float4* surv_box, float* surv_area,
        float4* cb4, float* car,
        const float* __restrict__ b20, const float* __restrict__ b40,
        const float* __restrict__ b80, float* __restrict__ out) {
    for (int base = 0; base < cnt && v < 100; base += 64) {
        const int i = base + t;
        const bool valid = (i < cnt);
        ull key = valid ? ssort[i] : 0ull;
        float4 B = make_float4(0.f, 0.f, 0.f, 0.f);
        float aB = 0.f, s = 0.f;
        if (valid) {
            int n = (int)(0xFFFFFFFFu - (unsigned)(key & 0xFFFFFFFFull));
            B = load_box(b, n, b20, b40, b80);
            aB = __fmul_rn(__fsub_rn(B.z, B.x), __fsub_rn(B.w, B.y));
            s = __uint_as_float((unsigned)(key >> 32));
        }
        cb4[t] = B;
        car[t] = aB;

        // vs already-accepted survivors (broadcast LDS reads, pipelined)
        bool supE = !valid;
        for (int j = 0; j < v; j++)
            supE |= iou_gt(surv_box[j], surv_area[j], B, aB);

        // pairwise within group: bit j set iff earlier member j suppresses me
        const int jmax = min(64, cnt - base);
        ull m = 0ull;
        for (int j = 0; j < jmax; j++) {
            bool sj = (j < t) && iou_gt(cb4[j], car[j], B, aB);
            m |= ((ull)sj) << j;
        }

        // wave-uniform greedy resolution
        ull alive = __ballot(!supE);
        while (alive != 0ull && v < 100) {
            int c = (int)(__ffsll(alive) - 1);
            ull supc = __ballot((bool)((m >> c) & 1ull));
            alive &= ~(supc | (1ull << c));
            if (t == c) {
                surv_box[v] = B;
                surv_area[v] = aB;
                float* row = out + ((size_t)b * 100 + v) * 6;
                row[0] = fminf(fmaxf(B.x, 0.f), 1.f);
                row[1] = fminf(fmaxf(B.y, 0.f), 1.f);
                row[2] = fminf(fmaxf(B.z, 0.f), 1.f);
                row[3] = fminf(fmaxf(B.w, 0.f), 1.f);
                row[4] = s;
                row[5] = 0.f;
            }
            v++;
        }
    }
}

// ---------------------------------------------------------------------------
// Kernel 2: per-batch exact greedy NMS. Hot path: rank-sort prebuilt >=64.0
// list, group-mask walk. Cold path (never taken here): histogram chunk loop.
// ---------------------------------------------------------------------------
__global__ __launch_bounds__(256) void nms_kernel(
        const float* __restrict__ scores_g,
        const unsigned* __restrict__ cand_cnt,
        const ull* __restrict__ cand_keys,
        const float* __restrict__ b20, const float* __restrict__ b40,
        const float* __restrict__ b80, float* __restrict__ out) {
    __shared__ ull skraw[CAP];          // 16 KB
    __shared__ ull ssort[CAP];          // 16 KB
    __shared__ unsigned hist[NBINS];    // 16 KB (fallback only)
    __shared__ unsigned segT[256];
    __shared__ float4 surv_box[100];
    __shared__ float surv_area[100];
    __shared__ float4 cb4[64];
    __shared__ float car[64];
    __shared__ int sh_V, sh_lo, sh_hi;
    __shared__ unsigned sh_counter, sh_done, sh_total;

    const int t = threadIdx.x;
    const int b = blockIdx.x;
    const float* sc = scores_g + (size_t)b * NANCH;

    const unsigned cnt_raw = cand_cnt[b];
    const bool use_list = (cnt_raw <= (unsigned)CAP);
    const int cnt = use_list ? (int)cnt_raw : 0;

    for (int i = t; i < cnt; i += 256) skraw[i] = cand_keys[(size_t)b * CAP + i];
    if (t == 0) sh_V = 0;
    __syncthreads();

    // rank sort, descending (keys unique via idx in low word)
    for (int c = t; c < cnt; c += 256) {
        ull k = skraw[c];
        int r = 0;
#pragma unroll 8
        for (int j = 0; j < cnt; j++) r += (skraw[j] > k) ? 1 : 0;
        ssort[r] = k;
    }
    __syncthreads();

    int v = 0;
    if (t < 64) {
        walk_sorted(ssort, cnt, t, b, v, surv_box, surv_area, cb4, car,
                    b20, b40, b80, out);
        if (t == 0) sh_V = v;
    }
    __syncthreads();

    // ---------------- exact fallback (not taken with this data) ------------
    if (sh_V < 100) {
        const int hi_start = use_list ? THR_BIN : NBINS;
        for (int i = t; i < NBINS; i += 256) hist[i] = 0u;
        if (t == 0) { sh_done = 0u; sh_hi = hi_start; }
        __syncthreads();
        for (int i = t; i < NANCH; i += 256) {
            float s = sc[i];
            if (s > SCORE_THR) {
                int bin = (int)(__float_as_uint(s) >> 20);
                if (bin < hi_start) atomicAdd(&hist[bin], 1u);
            }
        }
        __syncthreads();
        unsigned loc[16];
#pragma unroll
        for (int k = 0; k < 16; k++) loc[k] = hist[t * 16 + k];
#pragma unroll
        for (int k = 14; k >= 0; k--) loc[k] += loc[k + 1];
        segT[t] = loc[0];
        __syncthreads();
        for (int d = 1; d < 256; d <<= 1) {
            unsigned vv = (t + d < 256) ? segT[t + d] : 0u;
            __syncthreads();
            segT[t] += vv;
            __syncthreads();
        }
        {
            unsigned carry = (t < 255) ? segT[t + 1] : 0u;
#pragma unroll
            for (int k = 0; k < 16; k++) hist[t * 16 + k] = loc[k] + carry;
        }
        __syncthreads();
        if (t == 0) sh_total = hist[0];
        __syncthreads();

        for (int chunk = 0; chunk < 64; chunk++) {
            if (sh_V >= 100 || sh_done >= sh_total || sh_hi <= 0) break;
            const int hi = sh_hi;
            const unsigned Shi = (hi >= NBINS) ? 0u : hist[hi];
            if (t == 0) {
                int L = 0, R = hi;
                while (L < R) { int mm = (L + R) >> 1; if (hist[mm] - Shi <= (unsigned)CAP) R = mm; else L = mm + 1; }
                if (L >= hi) L = hi - 1;
                sh_lo = L;
                sh_counter = 0u;
            }
            __syncthreads();
            const int lo = sh_lo;
            for (int i = t; i < NANCH; i += 256) {
                float s = sc[i];
                if (s > SCORE_THR) {
                    int bin = (int)(__float_as_uint(s) >> 20);
                    if (bin >= lo && bin < hi) {
                        unsigned pos = atomicAdd(&sh_counter, 1u);
                        if (pos < (unsigned)CAP)
                            skraw[pos] = ((ull)__float_as_uint(s) << 32)
                                       | (ull)(0xFFFFFFFFu - (unsigned)i);
                    }
                }
            }
            __syncthreads();
            const int cc = min((int)sh_counter, CAP);
            for (int c = t; c < cc; c += 256) {
                ull k = skraw[c];
                int r = 0;
                for (int j = 0; j < cc; j++) r += (skraw[j] > k) ? 1 : 0;
                ssort[r] = k;
            }
            __syncthreads();
            if (t < 64) {
                walk_sorted(ssort, cc, t, b, v, surv_box, surv_area, cb4, car,
                            b20, b40, b80, out);
                if (t == 0) sh_V = v;
            }
            __syncthreads();
            if (t == 0) { sh_done += (unsigned)cc; sh_hi = lo; }
            __syncthreads();
        }
    }
    __syncthreads();

    const int V = sh_V;
    for (int i = V * 6 + t; i < 600; i += 256) out[(size_t)b * 600 + i] = 0.f;
    if (t == 0) out[4800 + b] = (float)V;
}

extern "C" void kernel_launch(void* const* d_in, const int* in_sizes, int n_in,
                              void* d_out, int out_size, void* d_ws, size_t ws_size,
                              hipStream_t stream) {
    const float* b20 = (const float*)d_in[0];
    const float* p20 = (const float*)d_in[1];
    const float* c20 = (const float*)d_in[2];
    const float* b40 = (const float*)d_in[3];
    const float* p40 = (const float*)d_in[4];
    const float* c40 = (const float*)d_in[5];
    const float* b80 = (const float*)d_in[6];
    const float* p80 = (const float*)d_in[7];
    const float* c80 = (const float*)d_in[8];

    float*    scores   = (float*)d_ws;                                   // 806400 B
    unsigned* cand_cnt = (unsigned*)((char*)d_ws + 806400);              // 32 B
    ull*      cand_keys = (ull*)((char*)d_ws + 806432);                  // 8*CAP*8 B

    hipMemsetAsync(cand_cnt, 0, BATCH * sizeof(unsigned), stream);

    dim3 sgrid((NANCH + 63) / 64, BATCH);
    score_kernel<<<sgrid, 256, 0, stream>>>(
        p20, c20, p40, c40, p80, c80, scores, cand_cnt, cand_keys);

    nms_kernel<<<BATCH, 256, 0, stream>>>(
        scores, cand_cnt, cand_keys, b20, b40, b80, (float*)d_out);
}